// Round 4
// baseline (265.660 us; speedup 1.0000x reference)
//
#include <hip/hip_runtime.h>
#include <hip/hip_bf16.h>
#include <stdint.h>

typedef unsigned short u16;
typedef unsigned int u32;
typedef __attribute__((ext_vector_type(8))) __bf16 bfrag;
typedef __attribute__((ext_vector_type(4))) float f32x4;
typedef __attribute__((ext_vector_type(16))) float f32x16;
typedef __attribute__((ext_vector_type(4))) unsigned short u16x4;

__device__ __forceinline__ u16 f2bf(float f){
  union { float f; u32 u; } v; v.f = f;
  u32 u = v.u;
  return (u16)((u + 0x7fffu + ((u >> 16) & 1u)) >> 16);
}

__device__ __forceinline__ u32 cvtpk(float a, float b){
  u32 r; asm("v_cvt_pk_bf16_f32 %0, %1, %2" : "=v"(r) : "v"(a), "v"(b)); return r;
}
__device__ __forceinline__ void swap32(u32 &a, u32 &b){
  asm volatile("v_permlane32_swap_b32 %0, %1" : "+v"(a), "+v"(b));
}

__device__ __forceinline__ void gload_lds16(const void* g, void* l){
  __builtin_amdgcn_global_load_lds(
      (__attribute__((address_space(1))) void*)(unsigned long long)g,
      (__attribute__((address_space(3))) void*)(u32)(unsigned long long)l,
      16, 0, 0);
}

// ---------------- converts ----------------
__global__ void __launch_bounds__(256) k_cvt(const float* __restrict__ s, u16* __restrict__ d, int n4){
  int i = blockIdx.x*256 + threadIdx.x;
  if (i >= n4) return;
  float4 v = ((const float4*)s)[i];
  u16x4 o; o[0]=f2bf(v.x); o[1]=f2bf(v.y); o[2]=f2bf(v.z); o[3]=f2bf(v.w);
  ((u16x4*)d)[i] = o;
}

// past_k [16][3072][128] f32 -> k_all [16][4096][128] bf16 (rows 0..3071)
__global__ void __launch_bounds__(256) k_cvt_past(const float* __restrict__ s, u16* __restrict__ d, int n4){
  int i = blockIdx.x*256 + threadIdx.x;
  if (i >= n4) return;
  int e = i*4;
  int row = e >> 7;
  int col = e & 127;
  int bh = row / 3072;
  int m = row - bh*3072;
  float4 v = ((const float4*)s)[i];
  u16x4 o; o[0]=f2bf(v.x); o[1]=f2bf(v.y); o[2]=f2bf(v.z); o[3]=f2bf(v.w);
  *(u16x4*)(d + ((size_t)(bh*4096 + m) << 7) + col) = o;
}

// past_v [16][3072][128] f32 -> v_t [16][128][4096] bf16 (cols 0..3071), transposed
__global__ void __launch_bounds__(256) k_cvt_past_vt(const float* __restrict__ s, u16* __restrict__ v_t){
  __shared__ u16 T[64][65];
  const int mt = blockIdx.x, dt = blockIdx.y, pl = blockIdx.z;
  const float* src = s + (size_t)pl*3072*128 + (size_t)mt*64*128 + dt*64;
  u16* dst = v_t + (size_t)pl*128*4096 + (size_t)dt*64*4096 + mt*64;
  const int t = threadIdx.x;
  #pragma unroll
  for (int r = 0; r < 2; ++r){
    int row = r*32 + (t >> 3);
    int c8 = (t & 7)*8;
    float4 va = *(const float4*)(src + (size_t)row*128 + c8);
    float4 vb = *(const float4*)(src + (size_t)row*128 + c8 + 4);
    T[row][c8+0]=f2bf(va.x); T[row][c8+1]=f2bf(va.y); T[row][c8+2]=f2bf(va.z); T[row][c8+3]=f2bf(va.w);
    T[row][c8+4]=f2bf(vb.x); T[row][c8+5]=f2bf(vb.y); T[row][c8+6]=f2bf(vb.z); T[row][c8+7]=f2bf(vb.w);
  }
  __syncthreads();
  #pragma unroll
  for (int r = 0; r < 2; ++r){
    int drow = r*32 + (t >> 3);
    int m8 = (t & 7)*8;
    union { bfrag v; u16 e[8]; } uv;
    #pragma unroll
    for (int j = 0; j < 8; ++j) uv.e[j] = T[m8 + j][drow];
    *(bfrag*)(dst + (size_t)drow*4096 + m8) = uv.v;
  }
}

// ---------------- GEMM C[M][N] = A[M][K] * B[N][K]^T ----------------
template<int EPI>
__global__ void __launch_bounds__(256) k_gemm(
    const u16* __restrict__ A, const u16* __restrict__ Bm,
    u16* __restrict__ Cb, float* __restrict__ Cf, const float* __restrict__ bias,
    int M, int Nn, int K)
{
  __shared__ u16 lsA[2][4096];
  __shared__ u16 lsB[2][4096];
  const int t = threadIdx.x, lane = t & 63, wid = t >> 6;
  const int l15 = lane & 15, l4 = lane >> 4;
  const int wm = wid >> 1, wn = wid & 1;
  const int bn = blockIdx.x, bm = blockIdx.y;
  const u16* Ab = A + (size_t)bm*128*K;
  const u16* Bb = Bm + (size_t)bn*128*K;

  auto stage = [&](u16* ls, const u16* g, int kof){
    #pragma unroll
    for (int r = 0; r < 2; ++r){
      int row = r*64 + (t >> 2);
      int s = (t & 3) ^ ((row >> 1) & 3);
      gload_lds16(g + (size_t)row*K + kof + s*8, ls + r*2048 + wid*512);
    }
  };

  f32x4 acc[4][4] = {};
  stage(&lsA[0][0], Ab, 0);
  stage(&lsB[0][0], Bb, 0);
  const int NT = K >> 5;
  const int sl = l4 ^ ((l15 >> 1) & 3);
  const int ra0 = wm*64 + l15, rb0 = wn*64 + l15;
  for (int kt = 0; kt < NT; ++kt){
    __syncthreads();
    const int cur = kt & 1;
    if (kt + 1 < NT){
      stage(&lsA[cur ^ 1][0], Ab, (kt + 1)*32);
      stage(&lsB[cur ^ 1][0], Bb, (kt + 1)*32);
    }
    bfrag af[4], bfv[4];
    #pragma unroll
    for (int i = 0; i < 4; ++i){
      af[i]  = *(const bfrag*)&lsA[cur][(ra0 + i*16)*32 + sl*8];
      bfv[i] = *(const bfrag*)&lsB[cur][(rb0 + i*16)*32 + sl*8];
    }
    #pragma unroll
    for (int i = 0; i < 4; ++i)
      #pragma unroll
      for (int j = 0; j < 4; ++j)
        acc[i][j] = __builtin_amdgcn_mfma_f32_16x16x32_bf16(af[i], bfv[j], acc[i][j], 0, 0, 0);
  }
  const int row0 = bm*128 + wm*64, col0 = bn*128 + wn*64;
  #pragma unroll
  for (int i = 0; i < 4; ++i)
    #pragma unroll
    for (int j = 0; j < 4; ++j){
      int cc = col0 + j*16 + l15;
      float bv = (EPI == 1) ? bias[cc] : 0.f;
      #pragma unroll
      for (int r = 0; r < 4; ++r){
        int rr = row0 + i*16 + l4*4 + r;
        if (EPI == 0) Cb[(size_t)rr*Nn + cc] = f2bf(acc[i][j][r]);
        else          Cf[(size_t)rr*Nn + cc] = acc[i][j][r] + bv;
      }
    }
}

// ---------------- fused RMSNorm + RoPE + scatter (q pre-scaled by log2e/sqrt(D)) ----------------
__global__ void __launch_bounds__(256) k_rmsrope(
    const u16* __restrict__ proj, const float* __restrict__ cosb, const float* __restrict__ sinb,
    const float* __restrict__ wq, const float* __restrict__ wk,
    u16* __restrict__ q_ro, u16* __restrict__ k_all, u16* __restrict__ v_all)
{
  const int bn = blockIdx.x;
  const int b = bn >> 10, n = bn & 1023;
  const int lane = threadIdx.x & 63, w = threadIdx.x >> 6;
  const int chunk = blockIdx.y*4 + w;
  const u16* src = proj + (size_t)bn*3072 + chunk*128 + lane*2;
  const u32 raw = *(const u32*)src;
  union { u32 u; float f; } a, c2;
  a.u = raw << 16; c2.u = raw & 0xffff0000u;
  float x0 = a.f, x1 = c2.f;
  if (chunk >= 20){
    int hk = chunk - 20;
    *(u32*)(v_all + (((size_t)(b*4 + hk)*4096 + 3072 + n) << 7) + lane*2) = raw;
    return;
  }
  float ss = x0*x0 + x1*x1;
  #pragma unroll
  for (int m = 1; m < 64; m <<= 1) ss += __shfl_xor(ss, m, 64);
  float inv = rsqrtf(ss*(1.f/128.f) + 1e-6f);
  const float* wn2 = (chunk < 16) ? wq : wk;
  x0 *= inv*wn2[lane*2]; x1 *= inv*wn2[lane*2 + 1];
  float cz = cosb[n*64 + lane], sz = sinb[n*64 + lane];
  float r0 = x0*cz - x1*sz;
  float r1 = x0*sz + x1*cz;
  if (chunk < 16){
    const float KLF = 0.127529904f;   // log2(e)/sqrt(128) folded into q
    r0 *= KLF; r1 *= KLF;
    u32 outp = (u32)f2bf(r0) | ((u32)f2bf(r1) << 16);
    *(u32*)(q_ro + (((size_t)(b*16 + chunk)*1024 + n) << 7) + lane*2) = outp;
  } else {
    int hk = chunk - 16;
    u32 outp = (u32)f2bf(r0) | ((u32)f2bf(r1) << 16);
    *(u32*)(k_all + (((size_t)(b*4 + hk)*4096 + 3072 + n) << 7) + lane*2) = outp;
  }
}

// ---------------- V transpose (new rows only): v_all[pl][m][d] -> v_t[pl][d][m] ----------------
__global__ void __launch_bounds__(256) k_transpose_v(const u16* __restrict__ v_all, u16* __restrict__ v_t){
  __shared__ u16 T[64][65];
  const int mt = blockIdx.x + 48, dt = blockIdx.y, pl = blockIdx.z;
  const u16* src = v_all + (size_t)pl*4096*128 + (size_t)mt*64*128 + dt*64;
  u16* dst = v_t + (size_t)pl*128*4096 + (size_t)dt*64*4096 + mt*64;
  const int t = threadIdx.x;
  #pragma unroll
  for (int r = 0; r < 2; ++r){
    int row = r*32 + (t >> 3);
    int c8 = (t & 7)*8;
    bfrag v = *(const bfrag*)(src + (size_t)row*128 + c8);
    union { bfrag v; u16 e[8]; } uv; uv.v = v;
    #pragma unroll
    for (int j = 0; j < 8; ++j) T[row][c8 + j] = uv.e[j];
  }
  __syncthreads();
  #pragma unroll
  for (int r = 0; r < 2; ++r){
    int drow = r*32 + (t >> 3);
    int m8 = (t & 7)*8;
    union { bfrag v; u16 e[8]; } uv;
    #pragma unroll
    for (int j = 0; j < 8; ++j) uv.e[j] = T[m8 + j][drow];
    *(bfrag*)(dst + (size_t)drow*4096 + m8) = uv.v;
  }
}

// ---------------- flash attention: no-max softmax, k-split waves ----------------
// grid 512: (b,hk,qt32); 8 waves = 4 heads x 2 k-halves; 2 blocks/CU -> 16 waves/CU
// LDS bytes: K[buf] at 16384*buf (16KB each); V[buf] at 32768 + 16384*buf.
__global__ void __launch_bounds__(512, 4) k_attn(
    const u16* __restrict__ q_ro, const u16* __restrict__ k_all,
    const u16* __restrict__ v_t, u16* __restrict__ attn_o)
{
  __shared__ u16 smem[32768];      // 64 KB
  __shared__ float Lsh[4][32];
  const int bid = blockIdx.x;
  const int xcd = bid & 7, idx = bid >> 3;
  const int plane = (xcd << 1) | (idx >> 5);
  const int qt = idx & 31;
  const int b = plane >> 2, hk = plane & 3;
  const int t = threadIdx.x, lane = t & 63, w = t >> 6;
  const int l31 = lane & 31, lh = lane >> 5;
  const int hf = w >> 2;           // k-half of chunk
  const int hd = w & 3;            // head within group
  const int h = hk*4 + hd;
  const int qbase = qt*32;

  const u16* qplane = q_ro + (size_t)(b*16 + h)*1024*128;
  const u16* kplane = k_all + (size_t)(b*4 + hk)*4096*128;
  const u16* vplane = v_t  + (size_t)(b*4 + hk)*128*4096;

  // Q B-frags: lane holds Q[qbase+l31][dks*16 + lh*8 + j]
  bfrag qf[8];
  {
    const u16* qrow = qplane + (size_t)(qbase + l31)*128 + lh*8;
    #pragma unroll
    for (int dks = 0; dks < 8; ++dks)
      qf[dks] = *(const bfrag*)(qrow + dks*16);
  }

  // staging thread offsets (elements)
  const int krow = t >> 4, kslot = t & 15;
  const int koff0 = krow*128 + ((kslot ^ (krow & 7))*8);       // +4096 elem for rows 32..63
  const int vrow = t >> 3, vslot = t & 7;
  const int voff0 = vrow*4096 + ((vslot ^ (vrow & 7))*8);      // +262144 elem for d rows 64..127

  // LDS read base addrs (bytes)
  const int swb = (lh << 4) ^ ((l31 & 7) << 4);
  const int kaddr = (hf*32 + l31)*256 + swb;
  const int vaddr = l31*128 + swb;

  const int kb0 = (qbase + 1024) & ~63;
  const int qpos = 3072 + qbase + l31;
  const char* smb = (const char*)smem;

  f32x16 acc_o[4] = {};
  float l_run = 0.f;

  // prologue stage -> buf0  (K at elem 0; V at elem 16384 == byte 32768)
  {
    const u16* kc = kplane + (size_t)kb0*128;
    const u16* vc = vplane + kb0;
    gload_lds16(kc + koff0,          smem + t*8);
    gload_lds16(kc + koff0 + 4096,   smem + 4096 + t*8);
    gload_lds16(vc + voff0,          smem + 16384 + t*8);
    gload_lds16(vc + voff0 + 262144, smem + 20480 + t*8);
  }

  for (int c = 0; c < 33; ++c){
    __syncthreads();
    const int cur = c & 1;
    if (c < 32){
      const u16* kc = kplane + (size_t)(kb0 + (c + 1)*64)*128;
      const u16* vc = vplane + kb0 + (c + 1)*64;
      u16* kd = smem + (cur ^ 1)*8192;
      u16* vd = smem + 16384 + (cur ^ 1)*8192;
      gload_lds16(kc + koff0,          kd + t*8);
      gload_lds16(kc + koff0 + 4096,   kd + 4096 + t*8);
      gload_lds16(vc + voff0,          vd + t*8);
      gload_lds16(vc + voff0 + 262144, vd + 4096 + t*8);
    }

    const int kaddrB = kaddr + cur*16384;
    const int vaddrB = vaddr + cur*16384;

    // S^T[k_local][q] = K_half · Q^T  (KL scale pre-folded into Q)
    f32x16 s = {};
    __builtin_amdgcn_s_setprio(1);
    #pragma unroll
    for (int dks = 0; dks < 8; ++dks){
      bfrag kf = *(const bfrag*)(smb + (kaddrB ^ (dks << 5)));
      s = __builtin_amdgcn_mfma_f32_32x32x16_bf16(kf, qf[dks], s, 0, 0, 0);
    }
    __builtin_amdgcn_s_setprio(0);

    if ((c == 0) | (c == 32)){
      const int kb = kb0 + c*64;
      #pragma unroll
      for (int r = 0; r < 16; ++r){
        int kpos = kb + hf*32 + (r & 3) + 8*(r >> 2) + 4*lh;
        int dq = qpos - kpos;
        if ((unsigned)dq >= 2048u) s[r] = -1e30f;
      }
    }

    // p = exp2(s); l += sum(p)  (no max tracking: |s_raw*KL| <= 16.3)
    #pragma unroll
    for (int r = 0; r < 16; ++r) s[r] = exp2f(s[r]);
    {
      float a0 = (s[0]+s[1]) + (s[2]+s[3]);
      float a1 = (s[4]+s[5]) + (s[6]+s[7]);
      float a2 = (s[8]+s[9]) + (s[10]+s[11]);
      float a3 = (s[12]+s[13]) + (s[14]+s[15]);
      float lc = (a0 + a1) + (a2 + a3);
      lc += __shfl_xor(lc, 32, 64);
      l_run += lc;
    }

    // P^T B-frags via cvt_pk + permlane32_swap
    union { u32 u[4]; bfrag v; } pf[2];
    {
      u32 a0 = cvtpk(s[0],  s[1]),  a1 = cvtpk(s[2],  s[3]);
      u32 b0 = cvtpk(s[4],  s[5]),  b1 = cvtpk(s[6],  s[7]);
      swap32(a0, b0); swap32(a1, b1);
      pf[0].u[0]=a0; pf[0].u[1]=a1; pf[0].u[2]=b0; pf[0].u[3]=b1;
      u32 c0 = cvtpk(s[8],  s[9]),  c1 = cvtpk(s[10], s[11]);
      u32 e0 = cvtpk(s[12], s[13]), e1 = cvtpk(s[14], s[15]);
      swap32(c0, e0); swap32(c1, e1);
      pf[1].u[0]=c0; pf[1].u[1]=c1; pf[1].u[2]=e0; pf[1].u[3]=e1;
    }

    // O^T[d][q] += V^T · P^T  (our k columns: ks = hf*2 + lks)
    __builtin_amdgcn_s_setprio(1);
    #pragma unroll
    for (int lks = 0; lks < 2; ++lks){
      const int va = vaddrB ^ ((hf*2 + lks) << 5);
      #pragma unroll
      for (int dj = 0; dj < 4; ++dj){
        bfrag vf = *(const bfrag*)(smb + 32768 + va + dj*4096);
        acc_o[dj] = __builtin_amdgcn_mfma_f32_32x32x16_bf16(vf, pf[lks].v, acc_o[dj], 0, 0, 0);
      }
    }
    __builtin_amdgcn_s_setprio(0);
  }

  // ---- merge k-halves through LDS ----
  __syncthreads();
  float* Om = (float*)smem;
  if (hf == 1){
    if (lh == 0) Lsh[hd][l31] = l_run;
    #pragma unroll
    for (int dj = 0; dj < 4; ++dj)
      #pragma unroll
      for (int rg = 0; rg < 4; ++rg){
        int slot = dj*8 + rg*2 + lh;
        f32x4 vv;
        #pragma unroll
        for (int j = 0; j < 4; ++j) vv[j] = acc_o[dj][rg*4 + j];
        *(f32x4*)&Om[hd*4096 + l31*128 + ((slot ^ (l31 & 7)) << 2)] = vv;
      }
  }
  __syncthreads();
  if (hf == 0){
    float ltot = l_run + Lsh[hd][l31];
    float inv = 1.0f / ltot;
    const int bn = b*1024 + qbase + l31;
    u16* orow = attn_o + (size_t)bn*2048 + h*128;
    #pragma unroll
    for (int dj = 0; dj < 4; ++dj)
      #pragma unroll
      for (int rg = 0; rg < 4; ++rg){
        int slot = dj*8 + rg*2 + lh;
        f32x4 vv = *(const f32x4*)&Om[hd*4096 + l31*128 + ((slot ^ (l31 & 7)) << 2)];
        int d0 = dj*32 + rg*8 + lh*4;
        u16x4 o;
        #pragma unroll
        for (int j = 0; j < 4; ++j) o[j] = f2bf((acc_o[dj][rg*4 + j] + vv[j])*inv);
        *(u16x4*)(orow + d0) = o;
      }
  }
}

// ---------------- launch ----------------
extern "C" void kernel_launch(void* const* d_in, const int* in_sizes, int n_in,
                              void* d_out, int out_size, void* d_ws, size_t ws_size,
                              hipStream_t stream)
{
  const float* x      = (const float*)d_in[0];
  const float* past_k = (const float*)d_in[1];
  const float* past_v = (const float*)d_in[2];
  const float* fcos   = (const float*)d_in[3];
  const float* fsin   = (const float*)d_in[4];
  const float* Wq     = (const float*)d_in[5];
  const float* Wk     = (const float*)d_in[6];
  const float* Wv     = (const float*)d_in[7];
  const float* Wo     = (const float*)d_in[8];
  const float* bo     = (const float*)d_in[9];
  const float* wqn    = (const float*)d_in[10];
  const float* wkn    = (const float*)d_in[11];
  float* out = (float*)d_out;
  char* ws = (char*)d_ws;

  u16* xb    = (u16*)(ws);
  u16* wqkv  = (u16*)(ws + 16777216);
  u16* wo_b  = (u16*)(ws + 29360128);
  u16* q_ro  = (u16*)(ws + 37748736);
  u16* k_all = (u16*)(ws + 54525952);
  u16* v_all = (u16*)(ws + 71303168);
  u16* v_t   = (u16*)(ws + 88080384);
  u16* proj  = (u16*)(ws + 104857600);
  u16* attn_o = proj;

  k_cvt<<<8192, 256, 0, stream>>>(x, xb, 2097152);
  k_cvt<<<4096, 256, 0, stream>>>(Wq, wqkv, 1048576);
  k_cvt<<<1024, 256, 0, stream>>>(Wk, wqkv + 2048*2048, 262144);
  k_cvt<<<1024, 256, 0, stream>>>(Wv, wqkv + 2560*2048, 262144);
  k_cvt<<<4096, 256, 0, stream>>>(Wo, wo_b, 1048576);
  k_cvt_past<<<6144, 256, 0, stream>>>(past_k, k_all, 1572864);
  k_cvt_past_vt<<<dim3(48, 2, 16), 256, 0, stream>>>(past_v, v_t);

  k_gemm<0><<<dim3(24, 32), 256, 0, stream>>>(xb, wqkv, proj, nullptr, nullptr, 4096, 3072, 2048);
  k_rmsrope<<<dim3(4096, 6), 256, 0, stream>>>(proj, fcos, fsin, wqn, wkn, q_ro, k_all, v_all);
  k_transpose_v<<<dim3(16, 2, 16), 256, 0, stream>>>(v_all, v_t);
  k_attn<<<512, 512, 0, stream>>>(q_ro, k_all, v_t, attn_o);
  k_gemm<1><<<dim3(16, 32), 256, 0, stream>>>(attn_o, wo_b, nullptr, out, bo, 4096, 2048, 2048);
}